// Round 6
// baseline (196.429 us; speedup 1.0000x reference)
//
#include <hip/hip_runtime.h>
#include <hip/hip_bf16.h>

// out[t][e] = (W[e][ids[t]] + b[e]) * sqrt(512)
// W: (512, 50257) row-major f32; ids: 32768 int32; out: 32768 x 512 f32.
//
// Round 6: wave-private pipelined transpose-scatter. No __syncthreads in the
// main kernel. Each wave owns (bucket, e-quarter): stages 32v x 64e chunks via
// global_load_lds into a private LDS slice, double-buffered with manual
// s_waitcnt vmcnt(32) so one chunk is always in flight during scatter.
// Theory: r4/r5's per-chunk drain-to-zero (barrier wall) idles HBM queues;
// r1 proved the memory system does 3.4+ TB/s on far worse patterns when issue
// is continuous.

constexpr int VOCAB = 50257;
constexpr int EMB   = 512;
constexpr int NTOK  = 8 * 4096;
constexpr float SCALE = 22.62741699796952f;  // sqrt(512)

constexpr int VB  = 32;                    // vocab ids per bucket
constexpr int NB  = (VOCAB + VB - 1) / VB; // 1571 buckets
constexpr int CAP = 128;                   // bucket capacity (mean 20.9, sigma 4.6)
constexpr int CH  = 64;                    // e-rows per chunk (2 chunks per wave-unit)
// wave-unit = (bucket, quarter of EMB): 1571*4 = 6284 units = 1571 blocks x 4 waves

// d_ws int layout: counts[NB] | ocount[1] | olist[NTOK] | buckets[NB*CAP]

__global__ __launch_bounds__(256) void init_counts(int* __restrict__ counts) {
    int i = blockIdx.x * 256 + threadIdx.x;
    if (i < NB + 1) counts[i] = 0;
}

__global__ __launch_bounds__(256) void build_buckets(
    const int* __restrict__ ids,
    int* __restrict__ counts,
    int* __restrict__ olist,
    int* __restrict__ buckets)
{
    int t = blockIdx.x * 256 + threadIdx.x;
    int id = ids[t];
    int bkt = id >> 5;                      // VB = 32
    int slot = atomicAdd(&counts[bkt], 1);
    if (slot < CAP) {
        buckets[bkt * CAP + slot] = (t << 5) | (id & 31);
    } else {
        int o = atomicAdd(&counts[NB], 1);
        olist[o] = t;
    }
}

__global__ __launch_bounds__(256) void scatter_main(
    const float* __restrict__ W,
    const float* __restrict__ bias,
    const int*   __restrict__ counts,
    const int*   __restrict__ buckets,
    float*       __restrict__ out)
{
    // Per wave: 2 buffers x 32 groups x 65 dwords (group = 2 e-rows x 32 v,
    // 64 dwords DMA'd + 1 pad dword). 4 waves x 2 x 2080 x 4B = 66,560 B.
    // Column read bank = (lane>>1 + vl) % 32 -> 2-way, free.
    __shared__ float tile[4][2][(CH / 2) * 65];

    int tid  = threadIdx.x;
    int w    = tid >> 6;
    int lane = tid & 63;

    int u = blockIdx.x * 4 + w;            // wave-unit, < 6284 exactly
    int b = u >> 2;                        // bucket
    int q = u & 3;                         // e-quarter
    int e_base = q * 128;

    int cnt = counts[b];                   // wave-uniform -> scalar load
    cnt = min(cnt, CAP);
    if (cnt == 0) return;

    // preload token list into lanes (coalesced); broadcast later via readlane
    const int* bk = buckets + b * CAP;
    int pk0 = bk[lane];
    int pk1 = bk[64 + lane];

    int vg = b * VB + (lane & 31);
    size_t vcl = (vg < VOCAB) ? (size_t)vg : (size_t)(VOCAB - 1);

    float* buf0 = &tile[w][0][0];
    float* buf1 = &tile[w][1][0];

    // ---- issue both chunks' DMAs back-to-back (64 outstanding) ----
    {
        const float* gp0 = W + (size_t)(e_base + (lane >> 5)) * VOCAB + vcl;
        #pragma unroll
        for (int g = 0; g < CH / 2; ++g)
            __builtin_amdgcn_global_load_lds(
                (const __attribute__((address_space(1))) void*)(gp0 + (size_t)(2 * g) * VOCAB),
                (__attribute__((address_space(3))) void*)(buf0 + g * 65), 4, 0, 0);
        const float* gp1 = W + (size_t)(e_base + CH + (lane >> 5)) * VOCAB + vcl;
        #pragma unroll
        for (int g = 0; g < CH / 2; ++g)
            __builtin_amdgcn_global_load_lds(
                (const __attribute__((address_space(1))) void*)(gp1 + (size_t)(2 * g) * VOCAB),
                (__attribute__((address_space(3))) void*)(buf1 + g * 65), 4, 0, 0);
    }

    int laddr = (lane >> 1) * 65 + (lane & 1) * 32;

    // ---- chunk 0: wait only the oldest 32 (chunk0); chunk1 stays in flight
    asm volatile("s_waitcnt vmcnt(32)" ::: "memory");
    {
        int e = e_base + lane;
        float bb = bias[e];
        for (int i = 0; i < cnt; ++i) {
            int pk = __builtin_amdgcn_readlane(i < 64 ? pk0 : pk1, i & 63);
            int t  = pk >> 5;
            int vl = pk & 31;
            out[(size_t)t * EMB + e] = (buf0[laddr + vl] + bb) * SCALE;
        }
    }

    // ---- chunk 1: need chunk1's DMAs done; stores are newer so vmcnt(0)
    asm volatile("s_waitcnt vmcnt(0)" ::: "memory");
    {
        int e = e_base + CH + lane;
        float bb = bias[e];
        for (int i = 0; i < cnt; ++i) {
            int pk = __builtin_amdgcn_readlane(i < 64 ? pk0 : pk1, i & 63);
            int t  = pk >> 5;
            int vl = pk & 31;
            out[(size_t)t * EMB + e] = (buf1[laddr + vl] + bb) * SCALE;
        }
    }
}

// Handles tokens whose bucket overflowed CAP (expected count: 0).
__global__ __launch_bounds__(256) void overflow_fix(
    const int*   __restrict__ counts,
    const int*   __restrict__ olist,
    const int*   __restrict__ ids,
    const float* __restrict__ W,
    const float* __restrict__ bias,
    float*       __restrict__ out)
{
    int n    = counts[NB];
    int wid  = (blockIdx.x * 256 + threadIdx.x) >> 6;
    int lane = threadIdx.x & 63;
    int nw   = (gridDim.x * 256) >> 6;
    for (int ww = wid; ww < n; ww += nw) {
        int t  = olist[ww];
        int id = ids[t];
        #pragma unroll
        for (int m = 0; m < 8; ++m) {
            int e = lane + m * 64;
            out[(size_t)t * EMB + e] = (W[(size_t)e * VOCAB + id] + bias[e]) * SCALE;
        }
    }
}

// Fallback (round-1 kernel) if d_ws is too small.
__global__ __launch_bounds__(256) void embed_gather(
    const int*   __restrict__ ids,
    const float* __restrict__ W,
    const float* __restrict__ b,
    float*       __restrict__ out)
{
    int idx4 = blockIdx.x * blockDim.x + threadIdx.x;
    int t    = idx4 >> 7;
    int e    = (idx4 & 127) << 2;
    int id = ids[t];
    float4 bb = *reinterpret_cast<const float4*>(b + e);
    const float* wcol = W + (size_t)id;
    float4 o;
    o.x = (wcol[(size_t)(e + 0) * VOCAB] + bb.x) * SCALE;
    o.y = (wcol[(size_t)(e + 1) * VOCAB] + bb.y) * SCALE;
    o.z = (wcol[(size_t)(e + 2) * VOCAB] + bb.z) * SCALE;
    o.w = (wcol[(size_t)(e + 3) * VOCAB] + bb.w) * SCALE;
    *reinterpret_cast<float4*>(out + (size_t)idx4 * 4) = o;
}

extern "C" void kernel_launch(void* const* d_in, const int* in_sizes, int n_in,
                              void* d_out, int out_size, void* d_ws, size_t ws_size,
                              hipStream_t stream)
{
    const int*   ids  = (const int*)  d_in[0];
    const float* W    = (const float*)d_in[1];
    const float* bias = (const float*)d_in[2];
    float*       out  = (float*)d_out;

    const size_t ws_ints_needed = (size_t)NB + 1 + NTOK + (size_t)NB * CAP;  // ~942 KB

    if (ws_size >= ws_ints_needed * sizeof(int)) {
        int* counts  = (int*)d_ws;
        int* olist   = counts + NB + 1;
        int* buckets = olist + NTOK;

        init_counts<<<(NB + 1 + 255) / 256, 256, 0, stream>>>(counts);
        build_buckets<<<NTOK / 256, 256, 0, stream>>>(ids, counts, olist, buckets);
        scatter_main<<<NB, 256, 0, stream>>>(W, bias, counts, buckets, out);
        overflow_fix<<<32, 256, 0, stream>>>(counts, olist, ids, W, bias, out);
    } else {
        constexpr int total4 = NTOK * EMB / 4;
        embed_gather<<<total4 / 256, 256, 0, stream>>>(ids, W, bias, out);
    }
}